// Round 1
// baseline (4416.960 us; speedup 1.0000x reference)
//
#include <hip/hip_runtime.h>
#include <math.h>

typedef unsigned short u16;
typedef unsigned int   u32;
typedef __bf16  bf16x8 __attribute__((ext_vector_type(8)));
typedef float   f32x4  __attribute__((ext_vector_type(4)));

#define Bz   8
#define Tz   512
#define Dz   1024
#define Hz   16
#define KVHz 4
#define HDz  64
#define Lz   4
#define Vz   32000
#define FFz  4096
#define Mz   (Bz*Tz)        // 4096
#define QKVz (Hz*HDz + 2*KVHz*HDz)  // 1536

// ---------- helpers ----------
__device__ __forceinline__ u16 bf16r(float f) {          // round-to-nearest-even fp32->bf16
    u32 u = __builtin_bit_cast(u32, f);
    u += 0x7fffu + ((u >> 16) & 1u);
    return (u16)(u >> 16);
}
__device__ __forceinline__ float b2f(u16 u) {
    u32 v = ((u32)u) << 16;
    return __builtin_bit_cast(float, v);
}
__device__ __forceinline__ float lo16(u32 u) { return __builtin_bit_cast(float, u << 16); }
__device__ __forceinline__ float hi16(u32 u) { return __builtin_bit_cast(float, u & 0xffff0000u); }
__device__ __forceinline__ float lane_bcast(float x, int l) {
    return __builtin_bit_cast(float, __builtin_amdgcn_readlane(__builtin_bit_cast(int, x), l));
}
__device__ __forceinline__ float wred_max(float x) {
#pragma unroll
    for (int m = 32; m > 0; m >>= 1) x = fmaxf(x, __shfl_xor(x, m, 64));
    return x;
}
__device__ __forceinline__ float wred_sum(float x) {
#pragma unroll
    for (int m = 32; m > 0; m >>= 1) x += __shfl_xor(x, m, 64);
    return x;
}
__device__ __forceinline__ void glds16(const void* g, void* l) {
    // async global->LDS, 16B per lane; LDS dest = wave-uniform base + lane*16
    __builtin_amdgcn_global_load_lds(
        (__attribute__((address_space(1))) unsigned int*)(unsigned long long)g,
        (__attribute__((address_space(3))) unsigned int*)l, 16, 0, 0);
}

// ---------- embedding gather ----------
__global__ __launch_bounds__(256) void embed_kernel(const int* __restrict__ ids,
                                                    const float* __restrict__ wte,
                                                    float* __restrict__ x) {
    const int row = blockIdx.x;
    const int id  = ids[row];
    ((float4*)(x + (size_t)row * Dz))[threadIdx.x] =
        ((const float4*)(wte + (size_t)id * Dz))[threadIdx.x];
}

// ---------- fp32 [K][N] -> bf16 [N][K] transpose+convert ----------
__global__ __launch_bounds__(256) void transpose_cvt_kernel(const float* __restrict__ in,
                                                            u16* __restrict__ out,
                                                            int K, int N) {
    __shared__ float tile[64][65];
    const size_t lofs = (size_t)blockIdx.z * (size_t)K * (size_t)N;
    const float* inp = in + lofs;
    u16* outp = out + lofs;
    const int nt = blockIdx.x << 6, kt = blockIdx.y << 6;
    const int c4 = (threadIdx.x & 15) << 2;
    const int r0 = threadIdx.x >> 4;
#pragma unroll
    for (int rr = 0; rr < 64; rr += 16) {
        const int r = rr + r0;
        float4 v = *(const float4*)(inp + (size_t)(kt + r) * N + nt + c4);
        tile[r][c4] = v.x; tile[r][c4 + 1] = v.y; tile[r][c4 + 2] = v.z; tile[r][c4 + 3] = v.w;
    }
    __syncthreads();
    const int n0 = threadIdx.x >> 2;
    const int kk = (threadIdx.x & 3) << 4;
    u16* ob = outp + (size_t)(nt + n0) * K + kt + kk;
#pragma unroll
    for (int g = 0; g < 4; ++g) {
        ushort4 uo;
        uo.x = bf16r(tile[kk + g * 4 + 0][n0]);
        uo.y = bf16r(tile[kk + g * 4 + 1][n0]);
        uo.z = bf16r(tile[kk + g * 4 + 2][n0]);
        uo.w = bf16r(tile[kk + g * 4 + 3][n0]);
        *(ushort4*)(ob + g * 4) = uo;
    }
}

// ---------- layernorm (fp32 in -> bf16 out) ----------
__global__ __launch_bounds__(256) void ln_kernel(const float* __restrict__ x,
                                                 const float* __restrict__ g,
                                                 const float* __restrict__ bb,
                                                 u16* __restrict__ out) {
    const int row = blockIdx.x;
    const float4 v = ((const float4*)(x + (size_t)row * Dz))[threadIdx.x];
    float s = v.x + v.y + v.z + v.w;
    float q = v.x * v.x + v.y * v.y + v.z * v.z + v.w * v.w;
#pragma unroll
    for (int m = 32; m > 0; m >>= 1) { s += __shfl_xor(s, m, 64); q += __shfl_xor(q, m, 64); }
    __shared__ float ss[4], qq[4];
    const int wid = threadIdx.x >> 6, lane = threadIdx.x & 63;
    if (lane == 0) { ss[wid] = s; qq[wid] = q; }
    __syncthreads();
    s = ss[0] + ss[1] + ss[2] + ss[3];
    q = qq[0] + qq[1] + qq[2] + qq[3];
    const float mean = s * (1.f / 1024.f);
    const float rstd = rsqrtf(q * (1.f / 1024.f) - mean * mean + 1e-5f);
    const float4 gv = ((const float4*)g)[threadIdx.x];
    const float4 bv = ((const float4*)bb)[threadIdx.x];
    ushort4 o;
    o.x = bf16r((v.x - mean) * rstd * gv.x + bv.x);
    o.y = bf16r((v.y - mean) * rstd * gv.y + bv.y);
    o.z = bf16r((v.z - mean) * rstd * gv.z + bv.z);
    o.w = bf16r((v.w - mean) * rstd * gv.w + bv.w);
    ((ushort4*)(out + (size_t)row * Dz))[threadIdx.x] = o;
}

// ---------- qkv fp32 -> rope'd q/k + v, bf16, head-major layouts ----------
__global__ __launch_bounds__(256) void rope_split_kernel(const float* __restrict__ qkv,
                                                         u16* __restrict__ q,
                                                         u16* __restrict__ k,
                                                         u16* __restrict__ v) {
    const int row = blockIdx.x;            // b*T + t
    const int b = row >> 9, t = row & 511;
    const float* src = qkv + (size_t)row * QKVz;
    const float ft = (float)t;
    for (int p = threadIdx.x; p < 512; p += 256) {   // q: 16 heads x 32 pairs
        const int h = p >> 5, i = p & 31;
        const float e = src[h * 64 + 2 * i], o = src[h * 64 + 2 * i + 1];
        const float ang = ft * exp2f((float)i * -0.41524101186092029f); // 10000^(-2i/64)
        float sn, cs; sincosf(ang, &sn, &cs);
        const size_t qi = (size_t)((b * 16 + h) * 512 + t) * 64 + 2 * i;
        q[qi]     = bf16r((e * cs - o * sn) * 0.125f);   // fold 1/sqrt(HD)
        q[qi + 1] = bf16r((e * sn + o * cs) * 0.125f);
    }
    for (int p = threadIdx.x; p < 128; p += 256) {   // k: 4 kv-heads x 32 pairs
        const int h = p >> 5, i = p & 31;
        const float e = src[1024 + h * 64 + 2 * i], o = src[1024 + h * 64 + 2 * i + 1];
        const float ang = ft * exp2f((float)i * -0.41524101186092029f);
        float sn, cs; sincosf(ang, &sn, &cs);
        const size_t ki = (size_t)((b * 4 + h) * 512 + t) * 64 + 2 * i;
        k[ki]     = bf16r(e * cs - o * sn);
        k[ki + 1] = bf16r(e * sn + o * cs);
    }
    for (int p = threadIdx.x; p < 128; p += 256) {   // v: no rope
        const int h = p >> 5, i = p & 31;
        const float e = src[1280 + 2 * p], o = src[1280 + 2 * p + 1];
        const size_t vi = (size_t)((b * 4 + h) * 512 + t) * 64 + 2 * i;
        v[vi] = bf16r(e); v[vi + 1] = bf16r(o);
    }
}

// ---------- flash attention, one wave per query row ----------
__global__ __launch_bounds__(256) void attn_kernel(const u16* __restrict__ q,
                                                   const u16* __restrict__ k,
                                                   const u16* __restrict__ v,
                                                   u16* __restrict__ y) {
    const int lane = threadIdx.x & 63;
    const size_t gw = (size_t)blockIdx.x * 4 + (threadIdx.x >> 6); // (b*H+h)*T + t
    const int t  = (int)(gw & 511);
    const int bh = (int)(gw >> 9);
    const int h = bh & 15, b = bh >> 4;
    const int kvh = h >> 2;
    const u16* kbase = k + (size_t)(b * 4 + kvh) * (512 * 64);
    const u16* vbase = v + (size_t)(b * 4 + kvh) * (512 * 64);
    const float qv = b2f(q[gw * 64 + lane]);     // lane holds q[d=lane], pre-scaled
    float mrun = -1e30f, lrun = 0.f, o = 0.f;    // lane holds o[d=lane]
    const int nchunk = (t >> 6) + 1;
    for (int c = 0; c < nchunk; ++c) {
        // lane j holds K row (c*64+j) in registers
        const uint4* kp = (const uint4*)(kbase + (size_t)(c * 64 + lane) * 64);
        float s = 0.f;
#pragma unroll
        for (int i = 0; i < 8; ++i) {
            const uint4 kq = kp[i];
            const int d = i * 8;
            s += lane_bcast(qv, d + 0) * lo16(kq.x) + lane_bcast(qv, d + 1) * hi16(kq.x);
            s += lane_bcast(qv, d + 2) * lo16(kq.y) + lane_bcast(qv, d + 3) * hi16(kq.y);
            s += lane_bcast(qv, d + 4) * lo16(kq.z) + lane_bcast(qv, d + 5) * hi16(kq.z);
            s += lane_bcast(qv, d + 6) * lo16(kq.w) + lane_bcast(qv, d + 7) * hi16(kq.w);
        }
        if (c * 64 + lane > t) s = -1e30f;       // causal mask
        const float cmax = wred_max(s);
        const float mnew = fmaxf(mrun, cmax);
        const float pe   = __expf(s - mnew);
        const float csum = wred_sum(pe);
        const float alpha = __expf(mrun - mnew);
        lrun = lrun * alpha + csum;
        o *= alpha;
        mrun = mnew;
        const u16* vc = vbase + (size_t)c * (64 * 64) + lane;  // lane reads column d=lane
#pragma unroll
        for (int j = 0; j < 64; ++j)
            o += lane_bcast(pe, j) * b2f(vc[j * 64]);
    }
    // y layout: [b][t][h*64+d]  (row-major A for proj GEMM)
    y[(size_t)(b * 512 + t) * 1024 + h * 64 + lane] = bf16r(o / lrun);
}

// ---------- bf16 MFMA GEMM: C[M,N] = A[M,K] @ Bt[N,K]^T  (+epilogue) ----------
// EPI: 0 = +bias -> f32 | 1 = +bias+resid -> f32 | 2 = +bias+gelu -> bf16 | 3 = plain -> f32
template <int EPI>
__global__ __launch_bounds__(256) void gemm_kernel(const u16* __restrict__ A,
                                                   const u16* __restrict__ Bt,
                                                   const float* __restrict__ bias,
                                                   const float* __restrict__ resid,
                                                   float* __restrict__ outF,
                                                   u16* __restrict__ outU,
                                                   int N, int K) {
    __shared__ __align__(16) u16 lA[4096];   // 4 kc-chunks x 128 rows x 8 bf16
    __shared__ __align__(16) u16 lB[4096];
    const int tid = threadIdx.x;
    const int wid = tid >> 6, lane = tid & 63;
    const int m0 = blockIdx.y << 7, n0 = blockIdx.x << 7;
    const int wm = (wid >> 1) << 6, wn = (wid & 1) << 6;
    const int kc = lane >> 4, l15 = lane & 15;

    // staging source pointers (pass0; pass1 = +16 elements)
    const u16* gA = A  + (size_t)(m0 + (tid & 127)) * K + ((tid >> 7) << 3);
    const u16* gB = Bt + (size_t)(n0 + (tid & 127)) * K + ((tid >> 7) << 3);
    u16* lA0 = &lA[wid << 9];  u16* lA1 = &lA[2048 + (wid << 9)];
    u16* lB0 = &lB[wid << 9];  u16* lB1 = &lB[2048 + (wid << 9)];

    f32x4 acc[4][4];
#pragma unroll
    for (int i = 0; i < 4; ++i)
#pragma unroll
        for (int j = 0; j < 4; ++j) acc[i][j] = (f32x4){0.f, 0.f, 0.f, 0.f};

    const bf16x8* lAv = (const bf16x8*)lA;
    const bf16x8* lBv = (const bf16x8*)lB;

    for (int k0 = 0; k0 < K; k0 += 32) {
        glds16(gA, lA0); glds16(gA + 16, lA1);
        glds16(gB, lB0); glds16(gB + 16, lB1);
        gA += 32; gB += 32;
        __syncthreads();                       // drains vmcnt -> LDS staged
        bf16x8 af[4], bfr[4];
#pragma unroll
        for (int tt = 0; tt < 4; ++tt) {
            af[tt]  = lAv[kc * 128 + wm + tt * 16 + l15];
            bfr[tt] = lBv[kc * 128 + wn + tt * 16 + l15];
        }
#pragma unroll
        for (int tm = 0; tm < 4; ++tm)
#pragma unroll
            for (int tn = 0; tn < 4; ++tn)
                acc[tm][tn] = __builtin_amdgcn_mfma_f32_16x16x32_bf16(af[tm], bfr[tn],
                                                                      acc[tm][tn], 0, 0, 0);
        __syncthreads();                       // protect LDS before next stage
    }

    const int rbase = (lane >> 4) << 2;
#pragma unroll
    for (int tn = 0; tn < 4; ++tn) {
        const int gc = n0 + wn + tn * 16 + l15;
        float bv = 0.f;
        if (EPI != 3) bv = bias[gc];
#pragma unroll
        for (int tm = 0; tm < 4; ++tm) {
#pragma unroll
            for (int r = 0; r < 4; ++r) {
                const int gr = m0 + wm + tm * 16 + rbase + r;
                const size_t idx = (size_t)gr * N + gc;
                float vv = acc[tm][tn][r] + bv;
                if (EPI == 1) vv += resid[idx];
                if (EPI == 2) {
                    const float gl = 0.5f * vv * (1.f + erff(vv * 0.70710678118654752f));
                    outU[idx] = bf16r(gl);
                } else {
                    outF[idx] = vv;
                }
            }
        }
    }
}

// ---------- host ----------
extern "C" void kernel_launch(void* const* d_in, const int* in_sizes, int n_in,
                              void* d_out, int out_size, void* d_ws, size_t ws_size,
                              hipStream_t stream) {
    const int*   ids      = (const int*)d_in[0];
    const float* wte      = (const float*)d_in[1];
    const float* ln1_g    = (const float*)d_in[2];
    const float* ln1_b    = (const float*)d_in[3];
    const float* c_attn_w = (const float*)d_in[4];
    const float* c_attn_b = (const float*)d_in[5];
    const float* c_proj_w = (const float*)d_in[6];
    const float* c_proj_b = (const float*)d_in[7];
    const float* ln2_g    = (const float*)d_in[8];
    const float* ln2_b    = (const float*)d_in[9];
    const float* fc_w     = (const float*)d_in[10];
    const float* fc_b     = (const float*)d_in[11];
    const float* proj_w   = (const float*)d_in[12];
    const float* proj_b   = (const float*)d_in[13];
    const float* lnf_g    = (const float*)d_in[14];
    const float* lnf_b    = (const float*)d_in[15];
    const float* lm_w     = (const float*)d_in[16];
    float* out = (float*)d_out;

    char* w = (char*)d_ws;
    auto take = [&](size_t bytes) { void* p = (void*)w; w += (bytes + 255) & ~(size_t)255; return p; };
    u16*   wqkvT = (u16*)take((size_t)Lz * QKVz * Dz * 2);   // [L][1536][1024]
    u16*   wprojT= (u16*)take((size_t)Lz * Dz * Dz * 2);     // [L][1024][1024]
    u16*   wfcT  = (u16*)take((size_t)Lz * FFz * Dz * 2);    // [L][4096][1024]
    u16*   wmlpT = (u16*)take((size_t)Lz * Dz * FFz * 2);    // [L][1024][4096]
    u16*   wlmT  = (u16*)take((size_t)Vz * Dz * 2);          // [32000][1024]
    float* x     = (float*)take((size_t)Mz * Dz * 4);
    u16*   h     = (u16*)take((size_t)Mz * Dz * 2);
    float* qkv   = (float*)take((size_t)Mz * QKVz * 4);
    u16*   qb    = (u16*)take((size_t)Mz * Dz * 2);
    u16*   kb    = (u16*)take((size_t)Bz * KVHz * Tz * HDz * 2);
    u16*   vb    = (u16*)take((size_t)Bz * KVHz * Tz * HDz * 2);
    u16*   yb    = (u16*)take((size_t)Mz * Dz * 2);
    u16*   mb    = (u16*)take((size_t)Mz * FFz * 2);
    (void)ws_size; (void)in_sizes; (void)n_in; (void)out_size;

    const dim3 tb(256);
    // weight convert+transpose (once per call; ws is re-poisoned every launch)
    transpose_cvt_kernel<<<dim3(QKVz / 64, Dz / 64, Lz), tb, 0, stream>>>(c_attn_w, wqkvT, Dz, QKVz);
    transpose_cvt_kernel<<<dim3(Dz / 64, Dz / 64, Lz), tb, 0, stream>>>(c_proj_w, wprojT, Dz, Dz);
    transpose_cvt_kernel<<<dim3(FFz / 64, Dz / 64, Lz), tb, 0, stream>>>(fc_w, wfcT, Dz, FFz);
    transpose_cvt_kernel<<<dim3(Dz / 64, FFz / 64, Lz), tb, 0, stream>>>(proj_w, wmlpT, FFz, Dz);
    transpose_cvt_kernel<<<dim3(Vz / 64, Dz / 64, 1), tb, 0, stream>>>(lm_w, wlmT, Dz, Vz);

    embed_kernel<<<Mz, tb, 0, stream>>>(ids, wte, x);

    for (int l = 0; l < Lz; ++l) {
        ln_kernel<<<Mz, tb, 0, stream>>>(x, ln1_g + l * Dz, ln1_b + l * Dz, h);
        gemm_kernel<0><<<dim3(QKVz / 128, Mz / 128), tb, 0, stream>>>(
            h, wqkvT + (size_t)l * QKVz * Dz, c_attn_b + l * QKVz, nullptr, qkv, nullptr, QKVz, Dz);
        rope_split_kernel<<<Mz, tb, 0, stream>>>(qkv, qb, kb, vb);
        attn_kernel<<<(Bz * Hz * Tz) / 4, tb, 0, stream>>>(qb, kb, vb, yb);
        gemm_kernel<1><<<dim3(Dz / 128, Mz / 128), tb, 0, stream>>>(
            yb, wprojT + (size_t)l * Dz * Dz, c_proj_b + l * Dz, x, x, nullptr, Dz, Dz);
        ln_kernel<<<Mz, tb, 0, stream>>>(x, ln2_g + l * Dz, ln2_b + l * Dz, h);
        gemm_kernel<2><<<dim3(FFz / 128, Mz / 128), tb, 0, stream>>>(
            h, wfcT + (size_t)l * FFz * Dz, fc_b + l * FFz, nullptr, nullptr, mb, FFz, Dz);
        gemm_kernel<1><<<dim3(Dz / 128, Mz / 128), tb, 0, stream>>>(
            mb, wmlpT + (size_t)l * Dz * FFz, proj_b + l * Dz, x, x, nullptr, Dz, FFz);
    }
    ln_kernel<<<Mz, tb, 0, stream>>>(x, lnf_g, lnf_b, h);
    gemm_kernel<3><<<dim3(Vz / 128, Mz / 128), tb, 0, stream>>>(
        h, wlmT, nullptr, nullptr, out, nullptr, Vz, Dz);
}